// Round 1
// baseline (588.876 us; speedup 1.0000x reference)
//
#include <hip/hip_runtime.h>
#include <math.h>

#define N_ROWS 131072
#define D 512
#define BLOCKS 2048
#define WPB 4
#define NWAVES (BLOCKS * WPB)                  // 8192 waves
#define ROWS_PER_WAVE (N_ROWS / NWAVES)        // 16
#define N_IT (ROWS_PER_WAVE / 2)               // 8 iterations x 2 rows
#define EPS 1e-6f

// numerically stable, branchless softplus: max(x,0) + log1p(exp(-|x|))
__device__ __forceinline__ float softplusf(float x) {
    return fmaxf(x, 0.0f) + log1pf(__expf(-fabsf(x)));
}

// 2 rows (one per 32-lane half), 4 x float4 per input per lane, straight to VGPRs
struct Frag {
    float4 a[4];
    float4 b[4];
};

__device__ __forceinline__ void issue_loads(const float* __restrict__ o1,
                                            const float* __restrict__ o2,
                                            size_t elem, Frag& f) {
    const float* p1 = o1 + elem;
    const float* p2 = o2 + elem;
    #pragma unroll
    for (int j = 0; j < 4; ++j) {
        f.a[j] = *(const float4*)(p1 + j * 128);
        f.b[j] = *(const float4*)(p2 + j * 128);
    }
}

__device__ __forceinline__ void process(const Frag& f, int t0, int t1, int rl, int sub,
                                        float& posAcc, float& negAcc, int& posCnt) {
    float dot = 0.0f, s1 = 0.0f, s2 = 0.0f;
    #pragma unroll
    for (int j = 0; j < 4; ++j) {
        float4 a = f.a[j];
        float4 v = f.b[j];
        dot += a.x * v.x + a.y * v.y + a.z * v.z + a.w * v.w;
        s1  += a.x * a.x + a.y * a.y + a.z * a.z + a.w * a.w;
        s2  += v.x * v.x + v.y * v.y + v.z * v.z + v.w * v.w;
    }
    // reduce across the 32 lanes of each row-group
    #pragma unroll
    for (int off = 16; off > 0; off >>= 1) {
        dot += __shfl_xor(dot, off);
        s1  += __shfl_xor(s1, off);
        s2  += __shfl_xor(s2, off);
    }
    if (sub == 0) {
        float d = dot / fmaxf(sqrtf(s1) * sqrtf(s2), EPS);
        int t = rl ? t1 : t0;
        if (t == 1) { posAcc += 4.0f * softplusf(-0.5f * (d - 0.5f)); posCnt++; }
        else        { negAcc += 0.04f * softplusf(50.0f * (d - 2.0f)); }
    }
}

__global__ __launch_bounds__(256, 4) void binloss_main(
    const float* __restrict__ o1, const float* __restrict__ o2,
    const int* __restrict__ target,
    float* __restrict__ sums, int* __restrict__ icnt,
    unsigned int* __restrict__ done, float* __restrict__ out) {

    __shared__ float sPos[WPB], sNeg[WPB];
    __shared__ int sCnt[WPB];

    const int lane = threadIdx.x & 63;
    const int wave = threadIdx.x >> 6;
    const int gwave = blockIdx.x * WPB + wave;
    const int rowBase = gwave * ROWS_PER_WAVE;
    const int sub = lane & 31;       // lane within row-group of 32
    const int rl = lane >> 5;        // which of the 2 rows this lane reduces

    // one small coalesced load: lane l holds target of the wave's (l&15)-th row
    const int myT = target[rowBase + (lane & (ROWS_PER_WAVE - 1))];

    const size_t colOff = (size_t)sub * 4;

    float posAcc = 0.0f, negAcc = 0.0f;
    int posCnt = 0;

    Frag fA, fB;
    // prologue: rows 0/1 into fA
    issue_loads(o1, o2, (size_t)(rowBase + rl) * D + colOff, fA);

    for (int k = 0; k < N_IT; k += 2) {
        // issue loads for iteration k+1 BEFORE consuming fA (depth-2 prefetch)
        issue_loads(o1, o2, (size_t)(rowBase + 2 * (k + 1) + rl) * D + colOff, fB);

        process(fA, __shfl(myT, 2 * k), __shfl(myT, 2 * k + 1), rl, sub,
                posAcc, negAcc, posCnt);

        if (k + 2 < N_IT)
            issue_loads(o1, o2, (size_t)(rowBase + 2 * (k + 2) + rl) * D + colOff, fA);

        process(fB, __shfl(myT, 2 * k + 2), __shfl(myT, 2 * k + 3), rl, sub,
                posAcc, negAcc, posCnt);
    }

    // only lanes 0 and 32 hold nonzero partials — one xor-32 combines them
    posAcc += __shfl_xor(posAcc, 32);
    negAcc += __shfl_xor(negAcc, 32);
    posCnt += __shfl_xor(posCnt, 32);

    if (lane == 0) { sPos[wave] = posAcc; sNeg[wave] = negAcc; sCnt[wave] = posCnt; }
    __syncthreads();
    if (threadIdx.x == 0) {
        float p = sPos[0] + sPos[1] + sPos[2] + sPos[3];
        float n = sNeg[0] + sNeg[1] + sNeg[2] + sNeg[3];
        int c = sCnt[0] + sCnt[1] + sCnt[2] + sCnt[3];
        atomicAdd(&sums[0], p);
        atomicAdd(&sums[1], n);
        atomicAdd(&icnt[0], c);
        __threadfence();
        unsigned int old = atomicAdd(done, 1u);
        if (old == (unsigned int)(gridDim.x - 1)) {
            __threadfence();
            float ps = __hip_atomic_load(&sums[0], __ATOMIC_RELAXED, __HIP_MEMORY_SCOPE_AGENT);
            float ns = __hip_atomic_load(&sums[1], __ATOMIC_RELAXED, __HIP_MEMORY_SCOPE_AGENT);
            int np = __hip_atomic_load(&icnt[0], __ATOMIC_RELAXED, __HIP_MEMORY_SCOPE_AGENT);
            int nn = N_ROWS - np;
            out[0] = ps / (float)(np > 1 ? np : 1) + ns / (float)(nn > 1 ? nn : 1);
        }
    }
}

extern "C" void kernel_launch(void* const* d_in, const int* in_sizes, int n_in,
                              void* d_out, int out_size, void* d_ws, size_t ws_size,
                              hipStream_t stream) {
    const float* o1 = (const float*)d_in[0];
    const float* o2 = (const float*)d_in[1];
    const int* tgt = (const int*)d_in[2];
    float* out = (float*)d_out;
    float* sums = (float*)d_ws;
    int* cnt = (int*)((char*)d_ws + 8);
    unsigned int* done = (unsigned int*)((char*)d_ws + 12);

    hipMemsetAsync(d_ws, 0, 16, stream);
    binloss_main<<<BLOCKS, 256, 0, stream>>>(o1, o2, tgt, sums, cnt, done, out);
}